// Round 6
// baseline (231.757 us; speedup 1.0000x reference)
//
#include <hip/hip_runtime.h>

// SparseProjector: out[b, idx[j]] = tau[b, j] * w[j], rest zeros.
// R6: R5 structure (XCD-aware row-groups, one fv4 NT store/thread/row,
// register-resident indices+weights) with a compacted index map:
//   inv16[p] : uint16 j      (na <= 65536 fits exactly)
//   mask[p/32] : 1 bit/pixel active flag
// inv stream 32 MB -> 17 MB; NT loads keep inv/mask from evicting tau in L2.

typedef int    iv4  __attribute__((ext_vector_type(4)));
typedef float  fv4  __attribute__((ext_vector_type(4)));
typedef unsigned short usv4 __attribute__((ext_vector_type(4)));

__global__ void zero_mask_kernel(unsigned int* __restrict__ mask, int nwords) {
    int t = blockIdx.x * blockDim.x + threadIdx.x;
    if (t < nwords) mask[t] = 0u;
}

__global__ void build_inv16_kernel(const int* __restrict__ idx,
                                   unsigned short* __restrict__ inv16,
                                   unsigned int* __restrict__ mask, int na) {
    int j = blockIdx.x * blockDim.x + threadIdx.x;
    if (j < na) {
        int pix = idx[j];
        inv16[pix] = (unsigned short)j;               // unique pixels -> no race
        atomicOr(&mask[pix >> 5], 1u << (pix & 31));
    }
}

// 1D grid: nseg * 8 blocks. bid&7 = row-group (== XCD under round-robin
// dispatch), bid>>3 = 1024-pixel segment. Each thread: 4 consecutive pixels.
__global__ __launch_bounds__(256)
void gather_rows_kernel(const float* __restrict__ tau,
                        const float* __restrict__ w,
                        const unsigned short* __restrict__ inv16,
                        const unsigned int* __restrict__ mask,
                        float* __restrict__ out,
                        int na, int p,
                        int rows_per_blk, int batch) {
    int bid = blockIdx.x;
    int rg  = bid & 7;          // row-group == XCD (round-robin assumption)
    int seg = bid >> 3;         // pixel segment
    int p4  = seg * blockDim.x + threadIdx.x;

    unsigned int mword = __builtin_nontemporal_load(&mask[p4 >> 3]);
    unsigned int nib = (mword >> ((p4 & 7) * 4)) & 0xFu;
    usv4 iv16 = __builtin_nontemporal_load((const usv4*)inv16 + p4);
    int j0 = iv16.x, j1 = iv16.y, j2 = iv16.z, j3 = iv16.w;

    float w0 = (nib & 1u) ? w[j0] : 0.0f;   // row-invariant weights, hoisted
    float w1 = (nib & 2u) ? w[j1] : 0.0f;
    float w2 = (nib & 4u) ? w[j2] : 0.0f;
    float w3 = (nib & 8u) ? w[j3] : 0.0f;

    int b0 = rg * rows_per_blk;
    int bend = b0 + rows_per_blk;
    if (bend > batch) bend = batch;

    const float* taub = tau + (size_t)b0 * (size_t)na;
    fv4* dst = (fv4*)(out + (size_t)b0 * (size_t)p) + p4;
    int pq = p >> 2;

    #pragma unroll 4
    for (int b = b0; b < bend; ++b) {
        fv4 o;
        o.x = (nib & 1u) ? taub[j0] * w0 : 0.0f;
        o.y = (nib & 2u) ? taub[j1] * w1 : 0.0f;
        o.z = (nib & 4u) ? taub[j2] * w2 : 0.0f;
        o.w = (nib & 8u) ? taub[j3] * w3 : 0.0f;
        __builtin_nontemporal_store(o, dst);  // full-line coalesced NT stream
        taub += na;
        dst += pq;
    }
}

// ---------- int32-inv path (na > 65536), R5 structure ----------
__global__ void fill_inv_kernel(int* __restrict__ inv, int n4) {
    int t = blockIdx.x * blockDim.x + threadIdx.x;
    int stride = gridDim.x * blockDim.x;
    iv4 m = (iv4)(-1);
    for (int i = t; i < n4; i += stride)
        ((iv4*)inv)[i] = m;
}

__global__ void build_inv_kernel(const int* __restrict__ idx,
                                 int* __restrict__ inv, int na) {
    int j = blockIdx.x * blockDim.x + threadIdx.x;
    if (j < na) inv[idx[j]] = j;
}

__global__ __launch_bounds__(256)
void gather_rows_i32_kernel(const float* __restrict__ tau,
                            const float* __restrict__ w,
                            const int* __restrict__ inv,
                            float* __restrict__ out,
                            int na, int p,
                            int rows_per_blk, int batch) {
    int bid = blockIdx.x;
    int rg  = bid & 7;
    int seg = bid >> 3;
    int p4  = seg * blockDim.x + threadIdx.x;

    iv4 iv = ((const iv4*)inv)[p4];
    float w0 = (iv.x >= 0) ? w[iv.x] : 0.0f;
    float w1 = (iv.y >= 0) ? w[iv.y] : 0.0f;
    float w2 = (iv.z >= 0) ? w[iv.z] : 0.0f;
    float w3 = (iv.w >= 0) ? w[iv.w] : 0.0f;

    int b0 = rg * rows_per_blk;
    int bend = b0 + rows_per_blk;
    if (bend > batch) bend = batch;

    const float* taub = tau + (size_t)b0 * (size_t)na;
    fv4* dst = (fv4*)(out + (size_t)b0 * (size_t)p) + p4;
    int pq = p >> 2;

    #pragma unroll 4
    for (int b = b0; b < bend; ++b) {
        fv4 o;
        o.x = (iv.x >= 0) ? taub[iv.x] * w0 : 0.0f;
        o.y = (iv.y >= 0) ? taub[iv.y] * w1 : 0.0f;
        o.z = (iv.z >= 0) ? taub[iv.z] * w2 : 0.0f;
        o.w = (iv.w >= 0) ? taub[iv.w] * w3 : 0.0f;
        __builtin_nontemporal_store(o, dst);
        taub += na;
        dst += pq;
    }
}

// ---------- last-resort fallback ----------
__global__ void zero_out_kernel(float* __restrict__ out, long long n4) {
    long long t = (long long)blockIdx.x * blockDim.x + threadIdx.x;
    long long stride = (long long)gridDim.x * blockDim.x;
    fv4 z = (fv4)(0.0f);
    for (long long i = t; i < n4; i += stride)
        __builtin_nontemporal_store(z, (fv4*)out + i);
}

__global__ void scatter_kernel(const float* __restrict__ tau,
                               const float* __restrict__ w,
                               const int* __restrict__ idx,
                               float* __restrict__ out,
                               int na, int p, int batch) {
    int j = blockIdx.x * blockDim.x + threadIdx.x;
    if (j >= na) return;
    int pix = idx[j];
    float ww = w[j];
    for (int b = 0; b < batch; ++b)
        out[(size_t)b * p + pix] = tau[(size_t)b * na + j] * ww;
}

extern "C" void kernel_launch(void* const* d_in, const int* in_sizes, int n_in,
                              void* d_out, int out_size, void* d_ws, size_t ws_size,
                              hipStream_t stream) {
    const float* tau = (const float*)d_in[0];
    const float* w   = (const float*)d_in[1];
    const int*   idx = (const int*)d_in[2];
    float* out = (float*)d_out;

    int na = in_sizes[1];                        // 65536
    int batch = in_sizes[0] / na;                // 256
    int p = (int)((long long)out_size / batch);  // 1048576

    const int ROW_GROUPS = 8;                    // == NXCD
    int rows_per_blk = (batch + ROW_GROUPS - 1) / ROW_GROUPS;  // 32
    int nseg = p / 1024;

    size_t need16 = (size_t)p * 2 + (size_t)(p / 8);
    if (na <= 65536 && (p % 1024) == 0 && batch >= 8 && ws_size >= need16) {
        unsigned short* inv16 = (unsigned short*)d_ws;
        unsigned int*   mask  = (unsigned int*)((char*)d_ws + (size_t)p * 2);
        int nwords = p / 32;
        zero_mask_kernel<<<dim3((nwords + 255) / 256), dim3(256), 0, stream>>>(mask, nwords);
        build_inv16_kernel<<<dim3((na + 255) / 256), dim3(256), 0, stream>>>(idx, inv16, mask, na);
        gather_rows_kernel<<<dim3(nseg * ROW_GROUPS), dim3(256), 0, stream>>>(
            tau, w, inv16, mask, out, na, p, rows_per_blk, batch);
    } else if (ws_size >= (size_t)p * sizeof(int) && (p % 1024) == 0 && batch >= 8) {
        int* inv = (int*)d_ws;
        int n4 = p / 4;
        fill_inv_kernel<<<dim3(1024), dim3(256), 0, stream>>>(inv, n4);
        build_inv_kernel<<<dim3((na + 255) / 256), dim3(256), 0, stream>>>(idx, inv, na);
        gather_rows_i32_kernel<<<dim3(nseg * ROW_GROUPS), dim3(256), 0, stream>>>(
            tau, w, inv, out, na, p, rows_per_blk, batch);
    } else {
        long long n4 = ((long long)out_size) / 4;
        zero_out_kernel<<<dim3(2048), dim3(256), 0, stream>>>(out, n4);
        scatter_kernel<<<dim3((na + 255) / 256), dim3(256), 0, stream>>>(
            tau, w, idx, out, na, p, batch);
    }
}

// Round 7
// 203.866 us; speedup vs baseline: 1.1368x; 1.1368x over previous
//
#include <hip/hip_runtime.h>

// SparseProjector: out[b, idx[j]] = tau[b, j] * w[j], rest zeros.
// R7 = exact revert to R5 (204 us, best). Ledger of proven structure:
//  - inverse-map gather, NOT scatter (R1: coalesced 1 GiB write stream)
//  - one fv4 NT store per thread per row (R4: 2 chunks/thread breaks wave
//    coalescing, 353 us; R3: plain stores trigger RFO-like 2x cost, 424 us)
//  - XCD-aware 1D grid: bid&7 = row-group == XCD -> each tau row fetched
//    by exactly one XCD's L2 (R5: 220 -> 204 us)
//  - int32 inv, plain loads (R6: uint16+bitmask+NT loads regressed, 232 us)

typedef int   iv4 __attribute__((ext_vector_type(4)));
typedef float fv4 __attribute__((ext_vector_type(4)));

__global__ void fill_inv_kernel(int* __restrict__ inv, int n4) {
    int t = blockIdx.x * blockDim.x + threadIdx.x;
    int stride = gridDim.x * blockDim.x;
    iv4 m = (iv4)(-1);
    for (int i = t; i < n4; i += stride)
        ((iv4*)inv)[i] = m;
}

__global__ void build_inv_kernel(const int* __restrict__ idx,
                                 int* __restrict__ inv, int na) {
    int j = blockIdx.x * blockDim.x + threadIdx.x;
    if (j < na) inv[idx[j]] = j;   // indices unique -> no race
}

// 1D grid: nseg * NXCD blocks. bid&7 = row-group (== XCD under round-robin
// dispatch), bid>>3 = 1024-pixel segment. Each thread: 4 consecutive pixels,
// rows_per_blk rows.
__global__ __launch_bounds__(256)
void gather_rows_kernel(const float* __restrict__ tau,
                        const float* __restrict__ w,
                        const int* __restrict__ inv,
                        float* __restrict__ out,
                        int na, int p,
                        int rows_per_blk, int batch) {
    int bid = blockIdx.x;
    int rg  = bid & 7;          // row-group == XCD (round-robin assumption)
    int seg = bid >> 3;         // pixel segment
    int p4  = seg * blockDim.x + threadIdx.x;

    iv4 iv = ((const iv4*)inv)[p4];          // read once, lives in VGPRs
    float w0 = (iv.x >= 0) ? w[iv.x] : 0.0f; // row-invariant weights, hoisted
    float w1 = (iv.y >= 0) ? w[iv.y] : 0.0f;
    float w2 = (iv.z >= 0) ? w[iv.z] : 0.0f;
    float w3 = (iv.w >= 0) ? w[iv.w] : 0.0f;

    int b0 = rg * rows_per_blk;
    int bend = b0 + rows_per_blk;
    if (bend > batch) bend = batch;

    const float* taub = tau + (size_t)b0 * (size_t)na;
    fv4* dst = (fv4*)(out + (size_t)b0 * (size_t)p) + p4;
    int pq = p >> 2;

    #pragma unroll 4
    for (int b = b0; b < bend; ++b) {
        fv4 o;
        o.x = (iv.x >= 0) ? taub[iv.x] * w0 : 0.0f;
        o.y = (iv.y >= 0) ? taub[iv.y] * w1 : 0.0f;
        o.z = (iv.z >= 0) ? taub[iv.z] * w2 : 0.0f;
        o.w = (iv.w >= 0) ? taub[iv.w] * w3 : 0.0f;
        __builtin_nontemporal_store(o, dst);  // full-line coalesced NT stream
        taub += na;
        dst += pq;
    }
}

// ---------- fallback path (only if ws_size too small for inv map) ----------
__global__ void zero_out_kernel(float* __restrict__ out, long long n4) {
    long long t = (long long)blockIdx.x * blockDim.x + threadIdx.x;
    long long stride = (long long)gridDim.x * blockDim.x;
    fv4 z = (fv4)(0.0f);
    for (long long i = t; i < n4; i += stride)
        __builtin_nontemporal_store(z, (fv4*)out + i);
}

__global__ void scatter_kernel(const float* __restrict__ tau,
                               const float* __restrict__ w,
                               const int* __restrict__ idx,
                               float* __restrict__ out,
                               int na, int p, int batch) {
    int j = blockIdx.x * blockDim.x + threadIdx.x;
    if (j >= na) return;
    int pix = idx[j];
    float ww = w[j];
    for (int b = 0; b < batch; ++b)
        out[(size_t)b * p + pix] = tau[(size_t)b * na + j] * ww;
}

extern "C" void kernel_launch(void* const* d_in, const int* in_sizes, int n_in,
                              void* d_out, int out_size, void* d_ws, size_t ws_size,
                              hipStream_t stream) {
    const float* tau = (const float*)d_in[0];
    const float* w   = (const float*)d_in[1];
    const int*   idx = (const int*)d_in[2];
    float* out = (float*)d_out;

    int na = in_sizes[1];                        // 65536
    int batch = in_sizes[0] / na;                // 256
    int p = (int)((long long)out_size / batch);  // 1048576

    if (ws_size >= (size_t)p * sizeof(int) && (p % 1024) == 0 && batch >= 8) {
        int* inv = (int*)d_ws;
        int n4 = p / 4;
        fill_inv_kernel<<<dim3(1024), dim3(256), 0, stream>>>(inv, n4);
        build_inv_kernel<<<dim3((na + 255) / 256), dim3(256), 0, stream>>>(idx, inv, na);

        const int ROW_GROUPS = 8;                            // == NXCD
        int rows_per_blk = (batch + ROW_GROUPS - 1) / ROW_GROUPS;  // 32
        int nseg = p / 1024;                                 // 1024 segments
        gather_rows_kernel<<<dim3(nseg * ROW_GROUPS), dim3(256), 0, stream>>>(
            tau, w, inv, out, na, p, rows_per_blk, batch);
    } else {
        long long n4 = ((long long)out_size) / 4;
        zero_out_kernel<<<dim3(2048), dim3(256), 0, stream>>>(out, n4);
        scatter_kernel<<<dim3((na + 255) / 256), dim3(256), 0, stream>>>(
            tau, w, idx, out, na, p, batch);
    }
}